// Round 9
// baseline (99.920 us; speedup 1.0000x reference)
//
#include <hip/hip_runtime.h>
#include <hip/hip_bf16.h>

#define NUP 8
#define NDOWN 8
#define NMO 32
#define NCONF 64
#define NBATCH 16384
#define ROWSTRIDE 33       // padded row stride (dwords): bank = (c + r) % 32 -> no column aliasing
#define PANEL (16 * ROWSTRIDE)  // 528 dwords per staged panel
#define NITER 4            // batches per slot (persistent loop with prefetch)

// 8x8 determinant via fully-unrolled Gaussian elimination with partial
// pivoting. All indices compile-time after unrolling -> stays in VGPRs
// (runtime-indexed register arrays would go to scratch, rule #20).
// Sign-free pivoting: {row_k <- row_i; row_i <- -row_k} preserves det and
// the negation folds into the cndmask source modifier; |.| compares are
// sign-blind so later pivot searches are unaffected.
__device__ __forceinline__ float det8(const float* __restrict__ base,
                                      int4 ca, int4 cb) {
    float m[8][8];
    const int cols[8] = {ca.x, ca.y, ca.z, ca.w, cb.x, cb.y, cb.z, cb.w};
#pragma unroll
    for (int j = 0; j < 8; ++j) {
        const float* cp = base + cols[j];
        // 8 reads at imm offsets i*132B; pairs merge into ds_read2_b32.
#pragma unroll
        for (int i = 0; i < 8; ++i) {
            m[i][j] = cp[i * ROWSTRIDE];
        }
    }

    float det = 1.0f;
#pragma unroll
    for (int k = 0; k < 8; ++k) {
        // Static compare-and-pseudo-swap chain: row k ends with the max-|.|
        // pivot among rows k..7 (same row choice as LAPACK, first-max ties).
#pragma unroll
        for (int i = k + 1; i < 8; ++i) {
            bool sw = fabsf(m[i][k]) > fabsf(m[k][k]);  // abs folds into v_cmp
#pragma unroll
            for (int j = k; j < 8; ++j) {
                float a = m[k][j], b = m[i][j];
                m[k][j] = sw ? b : a;
                m[i][j] = sw ? -a : b;   // neg folds into cndmask src modifier
            }
        }
        det *= m[k][k];
        if (k < 7) {
            // v_rcp_f32 (2^-22 rel err) vs ~10-instr IEEE divide; det error
            // stays ~1e-6 relative, same order as fp32 LU noise.
            float r = __builtin_amdgcn_rcpf(m[k][k]);
#pragma unroll
            for (int i = k + 1; i < 8; ++i) {
                float f = m[i][k] * r;
#pragma unroll
                for (int j = k + 1; j < 8; ++j) {
                    m[i][j] = fmaf(-f, m[k][j], m[i][j]);
                }
            }
        }
    }
    return det;
}

__global__ __launch_bounds__(256) void slater_kernel(
        const float* __restrict__ inp,     // [NBATCH][16][NMO] f32
        const int*   __restrict__ cup,     // [NCONF][NUP]
        const int*   __restrict__ cdown,   // [NCONF][NDOWN]
        float*       __restrict__ out)     // [NBATCH][NCONF]
{
    // Lane-split (lanes 0-31: det_up, lanes 32-63: det_dn, paired by
    // __shfl_xor(32)) + persistent NITER-batch loop per slot: the next
    // batch's panel loads are issued right after staging the current one,
    // so their ~900-cyc HBM latency hides under the ~1000-cyc det compute.
    // Index rows load ONCE and serve all NITER batches. No barriers: each
    // wave touches only its own panel; per-wave DS ordering covers both the
    // write->read (stage->gather) and read->write (gather->next-stage) deps.
    __shared__ float lds[4 * PANEL];   // 8448 B

    const int tid   = threadIdx.x;
    const int lane  = tid & 63;
    const int w     = tid >> 6;            // wave 0..3
    const int slot  = w >> 1;              // batch slot in block (0,1)
    const int wib   = w & 1;               // conf half
    const int conf  = wib * 32 + (lane & 31);
    const bool up   = (lane < 32);
    const int  pair = blockIdx.x * 2 + slot;   // 0..4095; covers batches pair*4..pair*4+3

    // Per-lane index row, loaded once for all NITER batches (L2-hot).
    const int* cbase = up ? cup : cdown;
    const int4 c0 = reinterpret_cast<const int4*>(cbase + conf * 8)[0];
    const int4 c1 = reinterpret_cast<const int4*>(cbase + conf * 8)[1];

    float* p = lds + w * PANEL;

    // Prologue: load panel for first batch of this slot.
    const float4* src = reinterpret_cast<const float4*>(inp + (size_t)(pair * NITER) * 16 * NMO);
    float4 a = src[lane];
    float4 b = src[lane + 64];

    const int e0 = lane >> 3;          // row 0..7
    const int m0 = (lane & 7) * 4;     // mo 0,4,..28
    const int e1 = e0 + 8;             // row 8..15

#pragma unroll
    for (int it = 0; it < NITER; ++it) {
        const int batch = pair * NITER + it;

        // Stage current panel (regs -> padded LDS).
        p[e0 * ROWSTRIDE + m0 + 0] = a.x;
        p[e0 * ROWSTRIDE + m0 + 1] = a.y;
        p[e0 * ROWSTRIDE + m0 + 2] = a.z;
        p[e0 * ROWSTRIDE + m0 + 3] = a.w;
        p[e1 * ROWSTRIDE + m0 + 0] = b.x;
        p[e1 * ROWSTRIDE + m0 + 1] = b.y;
        p[e1 * ROWSTRIDE + m0 + 2] = b.z;
        p[e1 * ROWSTRIDE + m0 + 3] = b.w;

        // Prefetch next batch's panel: issued before the det compute, so
        // the global-load latency hides under ~1000 cyc of VALU work.
        float4 na, nb;
        if (it < NITER - 1) {
            const float4* nsrc = reinterpret_cast<const float4*>(
                inp + (size_t)(batch + 1) * 16 * NMO);
            na = nsrc[lane];
            nb = nsrc[lane + 64];
        }

        // Compute this batch's det (up rows 0-7 / dn rows 8-15 by lane half).
        const float* base = p + (up ? 0 : 8 * ROWSTRIDE);
        const float det   = det8(base, c0, c1);

        // Pair lane L (det_up, conf) with lane L+32 (det_dn, same conf).
        const float other = __shfl_xor(det, 32);
        if (up) {
            out[(size_t)batch * NCONF + conf] = det * other;
        }

        a = na;  // reg copies; ds_writes above already consumed old a,b
        b = nb;
    }
}

extern "C" void kernel_launch(void* const* d_in, const int* in_sizes, int n_in,
                              void* d_out, int out_size, void* d_ws, size_t ws_size,
                              hipStream_t stream) {
    const float* inp   = reinterpret_cast<const float*>(d_in[0]);
    const int*   cup   = reinterpret_cast<const int*>(d_in[1]);
    const int*   cdown = reinterpret_cast<const int*>(d_in[2]);
    float*       out   = reinterpret_cast<float*>(d_out);

    dim3 grid(NBATCH / (2 * NITER));   // 2048 blocks, 2 slots each, NITER batches/slot
    dim3 block(256);
    slater_kernel<<<grid, block, 0, stream>>>(inp, cup, cdown, out);
}